// Round 7
// baseline (681.881 us; speedup 1.0000x reference)
//
#include <hip/hip_runtime.h>
#include <hip/hip_bf16.h>
#include <cstdint>
#include <cstddef>

#define B_   8192
#define D_   2048
#define H1_  1024
#define H2_  512
#define G_   512
#define T_   2
#define E_   6
#define EC_  4

typedef __bf16 bf16_t;
typedef __attribute__((ext_vector_type(8))) __bf16 bf16x8;
typedef __attribute__((ext_vector_type(4))) float f32x4;

// ---------------------------------------------------------------------------
// async global->LDS, 16B per lane. LDS dest is wave-uniform base + lane*16.
// ---------------------------------------------------------------------------
__device__ __forceinline__ void gload_lds16(const bf16_t* g, bf16_t* l) {
    __builtin_amdgcn_global_load_lds(
        (const __attribute__((address_space(1))) bf16_t*)g,
        (__attribute__((address_space(3))) bf16_t*)l,
        16, 0, 0);
}

// ---------------------------------------------------------------------------
// cast x (fp32) -> bf16, 8 elems/thread
// ---------------------------------------------------------------------------
__global__ __launch_bounds__(256) void cast_x_kernel(
    const float* __restrict__ src, bf16_t* __restrict__ dst, int n8)
{
    int i = blockIdx.x * blockDim.x + threadIdx.x;
    if (i >= n8) return;
    const float4* s = (const float4*)src + (size_t)i * 2;
    float4 a = s[0], b = s[1];
    bf16x8 o;
    o[0] = (bf16_t)a.x; o[1] = (bf16_t)a.y; o[2] = (bf16_t)a.z; o[3] = (bf16_t)a.w;
    o[4] = (bf16_t)b.x; o[5] = (bf16_t)b.y; o[6] = (bf16_t)b.z; o[7] = (bf16_t)b.w;
    *(bf16x8*)(dst + (size_t)i * 8) = o;
}

// ---------------------------------------------------------------------------
// transpose + cast: src (batch, R, C) fp32 -> dst (batch, C, R) bf16
// ---------------------------------------------------------------------------
__global__ __launch_bounds__(256) void transpose_cast_kernel(
    const float* __restrict__ src, bf16_t* __restrict__ dst, int R, int C)
{
    __shared__ float tile[32][33];
    int bz = blockIdx.z;
    src += (size_t)bz * R * C;
    dst += (size_t)bz * R * C;
    int c0 = blockIdx.x * 32, r0 = blockIdx.y * 32;
    int tx = threadIdx.x, ty = threadIdx.y;
#pragma unroll
    for (int i = 0; i < 32; i += 8)
        tile[ty + i][tx] = src[(size_t)(r0 + ty + i) * C + (c0 + tx)];
    __syncthreads();
#pragma unroll
    for (int i = 0; i < 32; i += 8)
        dst[(size_t)(c0 + ty + i) * R + (r0 + tx)] = (bf16_t)tile[tx][ty + i];
}

// ---------------------------------------------------------------------------
// 128x256-tile GEMM, A-direct-from-global (round 7):
//   C = relu(A(M,K)*Bt(N,K)^T + bias), bf16 in/out, fp32 MFMA accumulate.
// 8 waves (2M x 4N), per-wave 64x64 (acc = 64 AGPR). BK=32.
// A-fragments load global->VGPR directly (each 64-lane dwordx4 covers 16
// full 64B lines; 4-wave wr-group reuse -> L1/L2 hits). LDS carries ONLY B:
// 3 buffers x 16 KB = 48 KB -> 2 blocks/CU. LDS traffic 96 KB/CU-iter-pair
// (857 cyc) < MFMA demand (1030 cyc) -> MFMA-bound (r4 was LDS-bound at
// 176 KB/pair = ~127 B/cyc = ceiling).
// Schedule (r4-proven skeleton): ds_read b -> lgkm(0) -> barrier ->
//   STAGE_B(t+3 -> c) -> MFMA (compiler waits on a[] vmcnt) ->
//   A-loads(t+1) into a[] (WAR after MFMA) -> barrier.
// B(t+1) visibility: a(t) was issued AFTER B(t+2) (prev iter); in-order VMEM
// retirement means the compiler's a(t) wait before MFMA(t) implies
// B(t+1),B(t+2) complete; end barrier makes it cross-wave. Prologue uses one
// explicit vmcnt(0).
// XOR swizzle chunk ^= (row>>1)&3 on BOTH B-stage-source and ds_read
// (rule 21; conflict-free measured r2-r6).
// Requires: M%128==0, N%256==0, K%32==0, K/32>=4, gridX*gridY%8==0.
// ---------------------------------------------------------------------------
__global__ __launch_bounds__(512, 4) void gemm_adirect(
    const bf16_t* __restrict__ A, const bf16_t* __restrict__ Bt,
    const float* __restrict__ bias, bf16_t* __restrict__ C,
    int M, int N, int K, long long strideA)
{
    const int e = blockIdx.z;
    A    += (size_t)e * (size_t)strideA;
    Bt   += (size_t)e * (size_t)N * (size_t)K;
    bias += (size_t)e * (size_t)N;
    C    += (size_t)e * (size_t)M * (size_t)N;

    // T1: XCD swizzle within this z-slice (nwg % 8 == 0 by launch contract)
    const int gx  = gridDim.x;
    const int nwg = gx * gridDim.y;
    const int lin = blockIdx.y * gx + blockIdx.x;
    const int swz = (lin & 7) * (nwg >> 3) + (lin >> 3);
    const int row0 = (swz / gx) * 128;
    const int col0 = (swz % gx) * 256;

    __shared__ bf16_t lsB[3][8192];   // 3 x 16 KB (256 cols x 32 K)

    const int tid  = threadIdx.x;
    const int lane = tid & 63;
    const int wave = tid >> 6;        // 0..7
    const int wr   = wave >> 2;       // 0..1 : 64-row half
    const int wc   = wave & 3;        // 0..3 : 64-col quarter

    // ---- B staging (r4-proven): 2 loads/thread, XOR swizzle ----------------
    size_t offB0, offB1;
    {
        int r0_ = tid >> 2, p0_ = tid & 3;                 // slot = tid
        offB0 = (size_t)r0_ * (size_t)K + (size_t)(((p0_ ^ (r0_ >> 1)) & 3) * 8);
        int r1_ = (512 + tid) >> 2, p1_ = tid & 3;         // slot = 512 + tid
        offB1 = (size_t)r1_ * (size_t)K + (size_t)(((p1_ ^ (r1_ >> 1)) & 3) * 8);
    }
    const int ldsB0off = wave * 512;          // elements, wave-uniform
    const int ldsB1off = 4096 + wave * 512;
    const bf16_t* gB = Bt + (size_t)col0 * (size_t)K;

    // ---- B fragment read addressing (same XOR involution) ------------------
    const int xch  = ((lane >> 4) ^ ((lane >> 1) & 3)) << 3;
    const int boff = (wc * 64 + (lane & 15)) * 32 + xch;

    // ---- A direct-from-global fragment pointers (16B/lane, K-major) --------
    const bf16_t* pa = A + (size_t)(row0 + wr * 64 + (lane & 15)) * (size_t)K
                         + ((lane >> 4) << 3);
    const bf16_t* pa0 = pa;
    const bf16_t* pa1 = pa + (size_t)16 * (size_t)K;
    const bf16_t* pa2 = pa + (size_t)32 * (size_t)K;
    const bf16_t* pa3 = pa + (size_t)48 * (size_t)K;

    f32x4 acc[4][4];
#pragma unroll
    for (int m = 0; m < 4; ++m)
#pragma unroll
        for (int n = 0; n < 4; ++n)
            acc[m][n] = (f32x4){0.f, 0.f, 0.f, 0.f};

    const int nt = K >> 5;            // K-tiles of 32, nt >= 4

#define STAGEB(t_, c_) do {                                                   \
    const size_t kk_ = (size_t)(t_) * 32;                                     \
    gload_lds16(gB + kk_ + offB0, &lsB[c_][ldsB0off]);                        \
    gload_lds16(gB + kk_ + offB1, &lsB[c_][ldsB1off]);                        \
} while (0)

    // ---- prologue: stage B tiles 0,1,2; load A(0); full drain once ---------
    STAGEB(0, 0); STAGEB(1, 1); STAGEB(2, 2);
    bf16x8 a0 = *(const bf16x8*)pa0;
    bf16x8 a1 = *(const bf16x8*)pa1;
    bf16x8 a2 = *(const bf16x8*)pa2;
    bf16x8 a3 = *(const bf16x8*)pa3;
    asm volatile("s_waitcnt vmcnt(0)" ::: "memory");
    __builtin_amdgcn_s_barrier();
    __builtin_amdgcn_sched_barrier(0);

    int c = 0;
    for (int t = 0; t < nt; ++t) {
        bf16x8 b[4];
#pragma unroll
        for (int n = 0; n < 4; ++n)
            b[n] = *(const bf16x8*)&lsB[c][boff + n * 512];
        asm volatile("s_waitcnt lgkmcnt(0)" ::: "memory");
        __builtin_amdgcn_sched_barrier(0);
        __builtin_amdgcn_s_barrier();     // all waves done reading buf c
        __builtin_amdgcn_sched_barrier(0);
        if (t + 3 < nt) STAGEB(t + 3, c); // overwrite freed buffer
        __builtin_amdgcn_sched_barrier(0);
        __builtin_amdgcn_s_setprio(1);
#pragma unroll
        for (int n = 0; n < 4; ++n) {
            acc[0][n] = __builtin_amdgcn_mfma_f32_16x16x32_bf16(a0, b[n], acc[0][n], 0, 0, 0);
            acc[1][n] = __builtin_amdgcn_mfma_f32_16x16x32_bf16(a1, b[n], acc[1][n], 0, 0, 0);
            acc[2][n] = __builtin_amdgcn_mfma_f32_16x16x32_bf16(a2, b[n], acc[2][n], 0, 0, 0);
            acc[3][n] = __builtin_amdgcn_mfma_f32_16x16x32_bf16(a3, b[n], acc[3][n], 0, 0, 0);
        }
        __builtin_amdgcn_s_setprio(0);
        __builtin_amdgcn_sched_barrier(0);
        if (t + 1 < nt) {                 // A(t+1) into same regs (WAR-safe)
            const size_t ko = (size_t)(t + 1) * 32;
            a0 = *(const bf16x8*)(pa0 + ko);
            a1 = *(const bf16x8*)(pa1 + ko);
            a2 = *(const bf16x8*)(pa2 + ko);
            a3 = *(const bf16x8*)(pa3 + ko);
        }
        __builtin_amdgcn_sched_barrier(0);
        __builtin_amdgcn_s_barrier();     // B(t+1) visible to all waves
        __builtin_amdgcn_sched_barrier(0);
        c = (c == 2) ? 0 : c + 1;
    }
#undef STAGEB

    // ---- epilogue: C/D layout col = lane&15, row = (lane>>4)*4 + j ----------
    const int crb = row0 + wr * 64 + ((lane >> 4) << 2);
    const int ccb = col0 + wc * 64 + (lane & 15);
#pragma unroll
    for (int n = 0; n < 4; ++n) {
        const int cc = ccb + n * 16;
        const float bv = bias[cc];
#pragma unroll
        for (int m = 0; m < 4; ++m) {
            const int rb = crb + m * 16;
#pragma unroll
            for (int j = 0; j < 4; ++j) {
                float v = acc[m][n][j] + bv;
                v = v > 0.f ? v : 0.f;
                C[(size_t)(rb + j) * N + cc] = (bf16_t)v;
            }
        }
    }
}

// ---------------------------------------------------------------------------
// gate: logits[t,b,e] = sum_g g[t,b,g] * Wgs[t,g,e]; softmax over e (EC=4).
// g lives in h1 slice 6: row (t,b) at h1[(6*B + b)*1024 + t*512 ..].
// ---------------------------------------------------------------------------
__global__ __launch_bounds__(256) void gate_kernel(
    const bf16_t* __restrict__ h1, const float* __restrict__ Wgs,
    float* __restrict__ gate)
{
    int wid  = blockIdx.x * 4 + (threadIdx.x >> 6);   // t*B + b
    int lane = threadIdx.x & 63;
    int t = wid >> 13;                                // B_ = 8192
    int b = wid & (B_ - 1);
    const bf16_t* grow = h1 + ((size_t)(6 * B_) + b) * 1024 + t * G_;
    bf16x8 gv = *(const bf16x8*)&grow[lane * 8];
    const float* W = Wgs + (size_t)t * G_ * EC_;
    float a0 = 0.f, a1 = 0.f, a2 = 0.f, a3 = 0.f;
#pragma unroll
    for (int i = 0; i < 8; ++i) {
        float gvf = (float)gv[i];
        const float4 w = *(const float4*)&W[(size_t)(lane * 8 + i) * 4];
        a0 += gvf * w.x; a1 += gvf * w.y; a2 += gvf * w.z; a3 += gvf * w.w;
    }
#pragma unroll
    for (int off = 32; off; off >>= 1) {
        a0 += __shfl_xor(a0, off);
        a1 += __shfl_xor(a1, off);
        a2 += __shfl_xor(a2, off);
        a3 += __shfl_xor(a3, off);
    }
    if (lane == 0) {
        float m  = fmaxf(fmaxf(a0, a1), fmaxf(a2, a3));
        float e0 = expf(a0 - m), e1 = expf(a1 - m), e2 = expf(a2 - m), e3 = expf(a3 - m);
        float inv = 1.f / (e0 + e1 + e2 + e3);
        *(float4*)&gate[(size_t)wid * 4] = make_float4(e0 * inv, e1 * inv, e2 * inv, e3 * inv);
    }
}

// ---------------------------------------------------------------------------
// combine: out[t,b,o] = sum_j gate[t,b,j] * h2[IDX[t][j], b, o]
// ---------------------------------------------------------------------------
__global__ __launch_bounds__(256) void combine_kernel(
    const bf16_t* __restrict__ h2, const float* __restrict__ gate,
    float* __restrict__ out)
{
    size_t idx = (size_t)blockIdx.x * 256 + threadIdx.x;
    size_t tb  = idx >> 6;
    int    o0  = (int)(idx & 63) * 8;
    int    t   = (int)(tb >> 13);
    size_t b   = tb & (size_t)(B_ - 1);
    const float4 gv = *(const float4*)&gate[tb * 4];
    const bf16x8 v0 = *(const bf16x8*)&h2[((size_t)(2 * t)     * B_ + b) * H2_ + o0];
    const bf16x8 v1 = *(const bf16x8*)&h2[((size_t)(2 * t + 1) * B_ + b) * H2_ + o0];
    const bf16x8 v2 = *(const bf16x8*)&h2[((size_t)4           * B_ + b) * H2_ + o0];
    const bf16x8 v3 = *(const bf16x8*)&h2[((size_t)5           * B_ + b) * H2_ + o0];
    float r[8];
#pragma unroll
    for (int i = 0; i < 8; ++i)
        r[i] = gv.x * (float)v0[i] + gv.y * (float)v1[i]
             + gv.z * (float)v2[i] + gv.w * (float)v3[i];
    float4* op = (float4*)&out[tb * H2_ + o0];
    op[0] = make_float4(r[0], r[1], r[2], r[3]);
    op[1] = make_float4(r[4], r[5], r[6], r[7]);
}

// ---------------------------------------------------------------------------
extern "C" void kernel_launch(void* const* d_in, const int* in_sizes, int n_in,
                              void* d_out, int out_size, void* d_ws, size_t ws_size,
                              hipStream_t stream)
{
    const float* x   = (const float*)d_in[0];
    const float* We1 = (const float*)d_in[1];
    const float* be1 = (const float*)d_in[2];
    const float* We2 = (const float*)d_in[3];
    const float* be2 = (const float*)d_in[4];
    const float* Wg1 = (const float*)d_in[5];
    const float* bg1 = (const float*)d_in[6];
    const float* Wgs = (const float*)d_in[7];
    float* out = (float*)d_out;

    char* ws = (char*)d_ws;
    bf16_t* x_bf  = (bf16_t*)ws;  ws += (size_t)B_ * D_ * 2;             //  33.6 MB
    bf16_t* w1t   = (bf16_t*)ws;  ws += (size_t)7 * H1_ * D_ * 2;        //  29.4 MB (6 experts + gate)
    bf16_t* w2t   = (bf16_t*)ws;  ws += (size_t)E_ * H2_ * H1_ * 2;      //   6.3 MB
    bf16_t* h1    = (bf16_t*)ws;  ws += (size_t)7 * B_ * H1_ * 2;        // 117.4 MB (slice 6 = gate g)
    bf16_t* h2    = (bf16_t*)ws;  ws += (size_t)E_ * B_ * H2_ * 2;       //  50.3 MB
    float*  bias7 = (float*)ws;   ws += (size_t)7 * H1_ * 4;             //  28 KB
    float*  gate  = (float*)ws;   ws += (size_t)T_ * B_ * EC_ * 4;       //   0.3 MB

    bf16_t* wgt = w1t + (size_t)6 * H1_ * D_;   // gate weights = expert slice 6

    // 0) bias concat (d2d async, graph-capture safe)
    hipMemcpyAsync(bias7, be1, (size_t)E_ * H1_ * sizeof(float),
                   hipMemcpyDeviceToDevice, stream);
    hipMemcpyAsync(bias7 + (size_t)E_ * H1_, bg1, (size_t)T_ * G_ * sizeof(float),
                   hipMemcpyDeviceToDevice, stream);

    // 1) casts / transposes
    cast_x_kernel<<<(B_ * D_ / 8) / 256, 256, 0, stream>>>(x, x_bf, B_ * D_ / 8);
    dim3 tb(32, 8);
    transpose_cast_kernel<<<dim3(H1_ / 32, D_ / 32, E_),  tb, 0, stream>>>(We1, w1t, D_,  H1_);
    transpose_cast_kernel<<<dim3(H2_ / 32, H1_ / 32, E_), tb, 0, stream>>>(We2, w2t, H1_, H2_);
    transpose_cast_kernel<<<dim3(G_ / 32, D_ / 32, T_),   tb, 0, stream>>>(Wg1, wgt, D_,  G_);

    // 2) GEMM1 + gate folded (z = 0..5 experts, z = 6 gate)
    gemm_adirect<<<dim3(H1_ / 256, B_ / 128, 7), 512, 0, stream>>>(
        x_bf, w1t, bias7, h1, B_, H1_, D_, 0LL);
    // 3) GEMM2 over experts 0..5
    gemm_adirect<<<dim3(H2_ / 256, B_ / 128, E_), 512, 0, stream>>>(
        h1, w2t, be2, h2, B_, H2_, H1_, (long long)B_ * H1_);

    // 4) gate softmax + final combine
    gate_kernel<<<(T_ * B_) / 4, 256, 0, stream>>>(h1, Wgs, gate);
    combine_kernel<<<((size_t)T_ * B_ * H2_ / 8) / 256, 256, 0, stream>>>(h2, gate, out);
}

// Round 8
// 383.799 us; speedup vs baseline: 1.7767x; 1.7767x over previous
//
#include <hip/hip_runtime.h>
#include <hip/hip_bf16.h>
#include <cstdint>
#include <cstddef>

#define B_   8192
#define D_   2048
#define H1_  1024
#define H2_  512
#define G_   512
#define T_   2
#define E_   6
#define EC_  4

typedef __bf16 bf16_t;
typedef __attribute__((ext_vector_type(8))) __bf16 bf16x8;
typedef __attribute__((ext_vector_type(4))) float f32x4;

// ---------------------------------------------------------------------------
// async global->LDS, 16B per lane. LDS dest is wave-uniform base + lane*16.
// ---------------------------------------------------------------------------
__device__ __forceinline__ void gload_lds16(const bf16_t* g, bf16_t* l) {
    __builtin_amdgcn_global_load_lds(
        (const __attribute__((address_space(1))) bf16_t*)g,
        (__attribute__((address_space(3))) bf16_t*)l,
        16, 0, 0);
}

// ---------------------------------------------------------------------------
// cast x (fp32) -> bf16, 8 elems/thread
// ---------------------------------------------------------------------------
__global__ __launch_bounds__(256) void cast_x_kernel(
    const float* __restrict__ src, bf16_t* __restrict__ dst, int n8)
{
    int i = blockIdx.x * blockDim.x + threadIdx.x;
    if (i >= n8) return;
    const float4* s = (const float4*)src + (size_t)i * 2;
    float4 a = s[0], b = s[1];
    bf16x8 o;
    o[0] = (bf16_t)a.x; o[1] = (bf16_t)a.y; o[2] = (bf16_t)a.z; o[3] = (bf16_t)a.w;
    o[4] = (bf16_t)b.x; o[5] = (bf16_t)b.y; o[6] = (bf16_t)b.z; o[7] = (bf16_t)b.w;
    *(bf16x8*)(dst + (size_t)i * 8) = o;
}

// ---------------------------------------------------------------------------
// transpose + cast: src (batch, R, C) fp32 -> dst (batch, C, R) bf16
// ---------------------------------------------------------------------------
__global__ __launch_bounds__(256) void transpose_cast_kernel(
    const float* __restrict__ src, bf16_t* __restrict__ dst, int R, int C)
{
    __shared__ float tile[32][33];
    int bz = blockIdx.z;
    src += (size_t)bz * R * C;
    dst += (size_t)bz * R * C;
    int c0 = blockIdx.x * 32, r0 = blockIdx.y * 32;
    int tx = threadIdx.x, ty = threadIdx.y;
#pragma unroll
    for (int i = 0; i < 32; i += 8)
        tile[ty + i][tx] = src[(size_t)(r0 + ty + i) * C + (c0 + tx)];
    __syncthreads();
#pragma unroll
    for (int i = 0; i < 32; i += 8)
        dst[(size_t)(c0 + ty + i) * R + (r0 + tx)] = (bf16_t)tile[tx][ty + i];
}

// ---------------------------------------------------------------------------
// 256x256-tile, BK=64, 8-phase SINGLE-BARRIER-PER-PHASE GEMM (round 8):
//   C = relu(A(M,K) * Bt(N,K)^T + bias), bf16 in/out, fp32 MFMA accumulate.
// Same geometry/addressing as round 3 (correctness-proven): 8 waves (2Mx4N),
// per-wave 128x64, 2 LDS dbuf (128 KB), quadrant phases, B-frags read at
// qm==0 and held 4 phases.
// CHANGE vs r3: ONE barrier per phase, placed between {ds_read+stage issue}
// and the MFMA cluster (m201 template). reads/stage of phase p+1 overlap
// other waves' MFMA of phase p; skew bounded by 1 barrier.
// Hazards: lsB[buf] overwritten at p2/p3 -- all B-reads of that buf happened
// at p0 (before barrier(p0) <= barrier(p1) < stage(p2) issue)  OK.
// vmcnt(4) at p3/p7 BETWEEN stage and barrier: at wait(p3) queue =
// B(kt1)[4]+A(kt1)[4]+B(kt0+2)[4] -> leaves B(kt0+2) only, so A(kt1),B(kt1)
// complete before any wave's reads(p4) (barrier after wait broadcasts).
// Tail iter: wait(p3)=vmcnt(0). Prologue: A(0),B(0),B(1) then vmcnt(4).
// Requires: M%256==0, N%256==0, K%128==0, K/64>=4, gridX*gridY%8==0.
// ---------------------------------------------------------------------------
__global__ __launch_bounds__(512, 2) void gemm256_8p1b(
    const bf16_t* __restrict__ A, const bf16_t* __restrict__ Bt,
    const float* __restrict__ bias, bf16_t* __restrict__ C,
    int M, int N, int K, long long strideA)
{
    const int e = blockIdx.z;
    A    += (size_t)e * (size_t)strideA;
    Bt   += (size_t)e * (size_t)N * (size_t)K;
    bias += (size_t)e * (size_t)N;
    C    += (size_t)e * (size_t)M * (size_t)N;

    // T1: XCD swizzle within this z-slice (nwg % 8 == 0 by launch contract)
    const int gx  = gridDim.x;
    const int nwg = gx * gridDim.y;
    const int lin = blockIdx.y * gx + blockIdx.x;
    const int swz = (lin & 7) * (nwg >> 3) + (lin >> 3);
    const int bx  = swz % gx;
    const int by  = swz / gx;
    const int row0 = by * 256;
    const int col0 = bx * 256;

    __shared__ bf16_t lsA[2][16384];   // [dbuf][256 rows x 64], 64 KB
    __shared__ bf16_t lsB[2][16384];   // 64 KB

    const int tid  = threadIdx.x;
    const int lane = tid & 63;
    const int wave = tid >> 6;        // 0..7
    const int wr   = wave >> 2;       // 0..1 : M-half (128 rows)
    const int wc   = wave & 3;        // 0..3 : N-quarter (64 cols)

    // ---- staging geometry: one half-tile = 128 rows x 8 chunks(16B) --------
    // linear LDS slot idx = l*512 + tid sources logical chunk c = phys ^ (row&7)
    size_t offG[2];
    int    ldsOff[2];
#pragma unroll
    for (int l = 0; l < 2; ++l) {
        int idx = l * 512 + tid;
        int r   = idx >> 3;                       // row within half, 0..127
        int c   = (idx & 7) ^ (r & 7);            // logical chunk
        offG[l]   = (size_t)r * (size_t)K + (size_t)(c * 8);
        ldsOff[l] = l * 4096 + wave * 512;        // elements, wave-uniform
    }
    const bf16_t* gA = A  + (size_t)row0 * (size_t)K;
    const bf16_t* gB = Bt + (size_t)col0 * (size_t)K;
    const size_t halfStride = (size_t)128 * (size_t)K;

    // ---- fragment read addressing (elements), same XOR involution ----------
    const int rbA = (wr * 128 + (lane & 15)) * 64;
    const int rbB = (wc * 64  + (lane & 15)) * 64;
    int xc[2];
#pragma unroll
    for (int ks = 0; ks < 2; ++ks)
        xc[ks] = (ks * 32 + ((lane >> 4) * 8)) ^ ((lane & 7) << 3);

    f32x4 acc[8][4];
#pragma unroll
    for (int m = 0; m < 8; ++m)
#pragma unroll
        for (int n = 0; n < 4; ++n)
            acc[m][n] = (f32x4){0.f, 0.f, 0.f, 0.f};

    const int nt    = K >> 6;         // K-tiles of 64
    const int niter = nt >> 1;        // 2 K-tiles per iteration

#define STAGE_A(dst, kt, h) do {                                              \
    _Pragma("unroll")                                                         \
    for (int l_ = 0; l_ < 2; ++l_)                                            \
        gload_lds16(gA + (size_t)((kt) * 64) + (size_t)(h) * halfStride       \
                       + offG[l_],                                            \
                    &lsA[dst][(h) * 8192 + ldsOff[l_]]);                      \
} while (0)

#define STAGE_B(dst, kt, h) do {                                              \
    _Pragma("unroll")                                                         \
    for (int l_ = 0; l_ < 2; ++l_)                                            \
        gload_lds16(gB + (size_t)((kt) * 64) + (size_t)(h) * halfStride       \
                       + offG[l_],                                            \
                    &lsB[dst][(h) * 8192 + ldsOff[l_]]);                      \
} while (0)

// single-barrier phase: {ds_read quadrant [+B if qm==0]; stage; optional
// vmcnt; barrier; lgkm(0); 16 MFMA}.  WAITV must precede the barrier.
#define PHASE(d, qm, STMT, WAITV) do {                                        \
    bf16x8 af00, af01, af10, af11;                                            \
    af00 = *(const bf16x8*)&lsA[d][rbA + (2*(qm)+0) * 1024 + xc[0]];          \
    af01 = *(const bf16x8*)&lsA[d][rbA + (2*(qm)+0) * 1024 + xc[1]];          \
    af10 = *(const bf16x8*)&lsA[d][rbA + (2*(qm)+1) * 1024 + xc[0]];          \
    af11 = *(const bf16x8*)&lsA[d][rbA + (2*(qm)+1) * 1024 + xc[1]];          \
    if ((qm) == 0) {                                                          \
        _Pragma("unroll")                                                     \
        for (int n_ = 0; n_ < 4; ++n_) {                                      \
            bfr[n_][0] = *(const bf16x8*)&lsB[d][rbB + n_ * 1024 + xc[0]];    \
            bfr[n_][1] = *(const bf16x8*)&lsB[d][rbB + n_ * 1024 + xc[1]];    \
        }                                                                     \
    }                                                                         \
    STMT;                                                                     \
    WAITV;                                                                    \
    __builtin_amdgcn_sched_barrier(0);                                        \
    __builtin_amdgcn_s_barrier();                                             \
    asm volatile("s_waitcnt lgkmcnt(0)" ::: "memory");                        \
    __builtin_amdgcn_sched_barrier(0);                                        \
    __builtin_amdgcn_s_setprio(1);                                            \
    _Pragma("unroll")                                                         \
    for (int n_ = 0; n_ < 4; ++n_) {                                          \
        acc[2*(qm)+0][n_] = __builtin_amdgcn_mfma_f32_16x16x32_bf16(          \
                                af00, bfr[n_][0], acc[2*(qm)+0][n_], 0,0,0);  \
        acc[2*(qm)+0][n_] = __builtin_amdgcn_mfma_f32_16x16x32_bf16(          \
                                af01, bfr[n_][1], acc[2*(qm)+0][n_], 0,0,0);  \
        acc[2*(qm)+1][n_] = __builtin_amdgcn_mfma_f32_16x16x32_bf16(          \
                                af10, bfr[n_][0], acc[2*(qm)+1][n_], 0,0,0);  \
        acc[2*(qm)+1][n_] = __builtin_amdgcn_mfma_f32_16x16x32_bf16(          \
                                af11, bfr[n_][1], acc[2*(qm)+1][n_], 0,0,0);  \
    }                                                                         \
    __builtin_amdgcn_s_setprio(0);                                            \
    __builtin_amdgcn_sched_barrier(0);                                        \
} while (0)

    // ---- prologue: A(0),B(0) -> buf0; B(1) -> buf1; drain to 4 -------------
    STAGE_A(0, 0, 0); STAGE_A(0, 0, 1);
    STAGE_B(0, 0, 0); STAGE_B(0, 0, 1);
    STAGE_B(1, 1, 0); STAGE_B(1, 1, 1);
    asm volatile("s_waitcnt vmcnt(4)" ::: "memory");   // A(0),B(0) complete
    __builtin_amdgcn_sched_barrier(0);
    __builtin_amdgcn_s_barrier();
    __builtin_amdgcn_sched_barrier(0);

    // ---- main loop: iter i computes kt0=2i (buf0, p0-3), kt1=2i+1 (buf1) ---
    for (int i = 0; i < niter; ++i) {
        const int kt0 = 2 * i, kt1 = 2 * i + 1;
        const bool stg = (i + 1 < niter);
        bf16x8 bfr[4][2];

        PHASE(0, 0, { STAGE_A(1, kt1, 0); }, {});
        PHASE(0, 1, { STAGE_A(1, kt1, 1); }, {});
        PHASE(0, 2, { if (stg) STAGE_B(0, kt0 + 2, 0); }, {});
        PHASE(0, 3, { if (stg) STAGE_B(0, kt0 + 2, 1); },
              { if (stg) { asm volatile("s_waitcnt vmcnt(4)" ::: "memory"); }
                else     { asm volatile("s_waitcnt vmcnt(0)" ::: "memory"); } });
        PHASE(1, 0, { if (stg) STAGE_A(0, kt0 + 2, 0); }, {});
        PHASE(1, 1, { if (stg) STAGE_A(0, kt0 + 2, 1); }, {});
        PHASE(1, 2, { if (stg) STAGE_B(1, kt0 + 3, 0); }, {});
        PHASE(1, 3, { if (stg) STAGE_B(1, kt0 + 3, 1); },
              { if (stg) { asm volatile("s_waitcnt vmcnt(4)" ::: "memory"); } });
    }
#undef PHASE
#undef STAGE_A
#undef STAGE_B

    // ---- epilogue: C/D layout col = lane&15, row = (lane>>4)*4 + j ----------
    const int crb = row0 + wr * 128 + ((lane >> 4) << 2);
    const int ccb = col0 + wc * 64  + (lane & 15);
#pragma unroll
    for (int n = 0; n < 4; ++n) {
        const int cc = ccb + n * 16;
        const float bv = bias[cc];
#pragma unroll
        for (int m = 0; m < 8; ++m) {
            const int rb = crb + m * 16;
#pragma unroll
            for (int j = 0; j < 4; ++j) {
                float v = acc[m][n][j] + bv;
                v = v > 0.f ? v : 0.f;
                C[(size_t)(rb + j) * N + cc] = (bf16_t)v;
            }
        }
    }
}

// ---------------------------------------------------------------------------
// r4-proven 128x256 GEMM, 2 blocks/CU — used for GEMM2 (N=512 needs the
// 768-block grid; a 256^2 grid at 384 blocks would idle half the CUs).
// ---------------------------------------------------------------------------
__global__ __launch_bounds__(512, 4) void gemm_bn256_bias_relu(
    const bf16_t* __restrict__ A, const bf16_t* __restrict__ Bt,
    const float* __restrict__ bias, bf16_t* __restrict__ C,
    int M, int N, int K, long long strideA)
{
    const int e = blockIdx.z;
    A    += (size_t)e * (size_t)strideA;
    Bt   += (size_t)e * (size_t)N * (size_t)K;
    bias += (size_t)e * (size_t)N;
    C    += (size_t)e * (size_t)M * (size_t)N;

    const int gx  = gridDim.x;
    const int nwg = gx * gridDim.y;
    const int lin = blockIdx.y * gx + blockIdx.x;
    const int swz = (lin & 7) * (nwg >> 3) + (lin >> 3);
    const int row0 = (swz / gx) * 128;
    const int col0 = (swz % gx) * 256;

    __shared__ bf16_t lsA[3][128 * 32];   // 3 x 8 KB
    __shared__ bf16_t lsB[3][256 * 32];   // 3 x 16 KB   -> 72 KB total

    const int tid  = threadIdx.x;
    const int lane = tid & 63;
    const int wave = tid >> 6;        // 0..7
    const int wr   = wave >> 2;       // 0..1 : 64-row half
    const int wc   = wave & 3;        // 0..3 : 64-col quarter

    size_t offA, offB0, offB1;
    {
        int rA = tid >> 2, pA = tid & 3;
        offA = (size_t)rA * (size_t)K + (size_t)(((pA ^ (rA >> 1)) & 3) * 8);
        int r0_ = tid >> 2, p0_ = tid & 3;
        offB0 = (size_t)r0_ * (size_t)K + (size_t)(((p0_ ^ (r0_ >> 1)) & 3) * 8);
        int r1_ = (512 + tid) >> 2, p1_ = tid & 3;
        offB1 = (size_t)r1_ * (size_t)K + (size_t)(((p1_ ^ (r1_ >> 1)) & 3) * 8);
    }
    const int ldsA_off = wave * 512;
    const int ldsB0off = wave * 512;
    const int ldsB1off = 4096 + wave * 512;

    const bf16_t* gA = A  + (size_t)row0 * (size_t)K;
    const bf16_t* gB = Bt + (size_t)col0 * (size_t)K;

    const int xch  = ((lane >> 4) ^ ((lane >> 1) & 3)) << 3;
    const int aoff = (wr * 64 + (lane & 15)) * 32 + xch;
    const int boff = (wc * 64 + (lane & 15)) * 32 + xch;

    f32x4 acc[4][4];
#pragma unroll
    for (int m = 0; m < 4; ++m)
#pragma unroll
        for (int n = 0; n < 4; ++n)
            acc[m][n] = (f32x4){0.f, 0.f, 0.f, 0.f};

    const int nt = K >> 5;

#define STAGE(t_, c_) do {                                                    \
    const size_t kk_ = (size_t)(t_) * 32;                                     \
    gload_lds16(gA + kk_ + offA,  &lsA[c_][ldsA_off]);                        \
    gload_lds16(gB + kk_ + offB0, &lsB[c_][ldsB0off]);                        \
    gload_lds16(gB + kk_ + offB1, &lsB[c_][ldsB1off]);                        \
} while (0)

    STAGE(0, 0); STAGE(1, 1); STAGE(2, 2);
    asm volatile("s_waitcnt vmcnt(6)" ::: "memory");
    __builtin_amdgcn_s_barrier();
    __builtin_amdgcn_sched_barrier(0);

    int c = 0;
    for (int t = 0; t < nt; ++t) {
        bf16x8 a[4], b[4];
#pragma unroll
        for (int m = 0; m < 4; ++m)
            a[m] = *(const bf16x8*)&lsA[c][aoff + m * 512];
#pragma unroll
        for (int n = 0; n < 4; ++n)
            b[n] = *(const bf16x8*)&lsB[c][boff + n * 512];
        asm volatile("s_waitcnt lgkmcnt(0)" ::: "memory");
        __builtin_amdgcn_sched_barrier(0);
        __builtin_amdgcn_s_barrier();
        __builtin_amdgcn_sched_barrier(0);
        if (t + 3 < nt) STAGE(t + 3, c);
        __builtin_amdgcn_sched_barrier(0);
        __builtin_amdgcn_s_setprio(1);
#pragma unroll
        for (int m = 0; m < 4; ++m)
#pragma unroll
            for (int n = 0; n < 4; ++n)
                acc[m][n] = __builtin_amdgcn_mfma_f32_16x16x32_bf16(
                                a[m], b[n], acc[m][n], 0, 0, 0);
        __builtin_amdgcn_s_setprio(0);
        __builtin_amdgcn_sched_barrier(0);
        if (t + 3 < nt) { asm volatile("s_waitcnt vmcnt(6)" ::: "memory"); }
        else            { asm volatile("s_waitcnt vmcnt(0)" ::: "memory"); }
        __builtin_amdgcn_sched_barrier(0);
        __builtin_amdgcn_s_barrier();
        __builtin_amdgcn_sched_barrier(0);
        c = (c == 2) ? 0 : c + 1;
    }
#undef STAGE

    const int crb = row0 + wr * 64 + ((lane >> 4) << 2);
    const int ccb = col0 + wc * 64 + (lane & 15);
#pragma unroll
    for (int n = 0; n < 4; ++n) {
        const int cc = ccb + n * 16;
        const float bv = bias[cc];
#pragma unroll
        for (int m = 0; m < 4; ++m) {
            const int rb = crb + m * 16;
#pragma unroll
            for (int j = 0; j < 4; ++j) {
                float v = acc[m][n][j] + bv;
                v = v > 0.f ? v : 0.f;
                C[(size_t)(rb + j) * N + cc] = (bf16_t)v;
            }
        }
    }
}

// ---------------------------------------------------------------------------
// gate: logits[t,b,e] = sum_g g[t,b,g] * Wgs[t,g,e]; softmax over e (EC=4).
// g lives in h1 slice 6: row (t,b) at h1[(6*B + b)*1024 + t*512 ..].
// ---------------------------------------------------------------------------
__global__ __launch_bounds__(256) void gate_kernel(
    const bf16_t* __restrict__ h1, const float* __restrict__ Wgs,
    float* __restrict__ gate)
{
    int wid  = blockIdx.x * 4 + (threadIdx.x >> 6);   // t*B + b
    int lane = threadIdx.x & 63;
    int t = wid >> 13;                                // B_ = 8192
    int b = wid & (B_ - 1);
    const bf16_t* grow = h1 + ((size_t)(6 * B_) + b) * 1024 + t * G_;
    bf16x8 gv = *(const bf16x8*)&grow[lane * 8];
    const float* W = Wgs + (size_t)t * G_ * EC_;
    float a0 = 0.f, a1 = 0.f, a2 = 0.f, a3 = 0.f;
#pragma unroll
    for (int i = 0; i < 8; ++i) {
        float gvf = (float)gv[i];
        const float4 w = *(const float4*)&W[(size_t)(lane * 8 + i) * 4];
        a0 += gvf * w.x; a1 += gvf * w.y; a2 += gvf * w.z; a3 += gvf * w.w;
    }
#pragma unroll
    for (int off = 32; off; off >>= 1) {
        a0 += __shfl_xor(a0, off);
        a1 += __shfl_xor(a1, off);
        a2 += __shfl_xor(a2, off);
        a3 += __shfl_xor(a3, off);
    }
    if (lane == 0) {
        float m  = fmaxf(fmaxf(a0, a1), fmaxf(a2, a3));
        float e0 = expf(a0 - m), e1 = expf(a1 - m), e2 = expf(a2 - m), e3 = expf(a3 - m);
        float inv = 1.f / (e0 + e1 + e2 + e3);
        *(float4*)&gate[(size_t)wid * 4] = make_float4(e0 * inv, e1 * inv, e2 * inv, e3 * inv);
    }
}

// ---------------------------------------------------------------------------
// combine: out[t,b,o] = sum_j gate[t,b,j] * h2[IDX[t][j], b, o]
// ---------------------------------------------------------------------------
__global__ __launch_bounds__(256) void combine_kernel(
    const bf16_t* __restrict__ h2, const float* __restrict__ gate,
    float* __restrict__ out)
{
    size_t idx = (size_t)blockIdx.x * 256 + threadIdx.x;
    size_t tb  = idx >> 6;
    int    o0  = (int)(idx & 63) * 8;
    int    t   = (int)(tb >> 13);
    size_t b   = tb & (size_t)(B_ - 1);
    const float4 gv = *(const float4*)&gate[tb * 4];
    const bf16x8 v0 = *(const bf16x8*)&h2[((size_t)(2 * t)     * B_ + b) * H2_ + o0];
    const bf16x8 v1 = *(const bf16x8*)&h2[((size_t)(2 * t + 1) * B_ + b) * H2_ + o0];
    const bf16x8 v2 = *(const bf16x8*)&h2[((size_t)4           * B_ + b) * H2_ + o0];
    const bf16x8 v3 = *(const bf16x8*)&h2[((size_t)5           * B_ + b) * H2_ + o0];
    float r[8];
#pragma unroll
    for (int i = 0; i < 8; ++i)
        r[i] = gv.x * (float)v0[i] + gv.y * (float)v1[i]
             + gv.z * (float)v2[i] + gv.w * (float)v3[i];
    float4* op = (float4*)&out[tb * H2_ + o0];
    op[0] = make_float4(r[0], r[1], r[2], r[3]);
    op[1] = make_float4(r[4], r[5], r[6], r[7]);
}

// ---------------------------------------------------------------------------
extern "C" void kernel_launch(void* const* d_in, const int* in_sizes, int n_in,
                              void* d_out, int out_size, void* d_ws, size_t ws_size,
                              hipStream_t stream)
{
    const float* x   = (const float*)d_in[0];
    const float* We1 = (const float*)d_in[1];
    const float* be1 = (const float*)d_in[2];
    const float* We2 = (const float*)d_in[3];
    const float* be2 = (const float*)d_in[4];
    const float* Wg1 = (const float*)d_in[5];
    const float* bg1 = (const float*)d_in[6];
    const float* Wgs = (const float*)d_in[7];
    float* out = (float*)d_out;

    char* ws = (char*)d_ws;
    bf16_t* x_bf  = (bf16_t*)ws;  ws += (size_t)B_ * D_ * 2;             //  33.6 MB
    bf16_t* w1t   = (bf16_t*)ws;  ws += (size_t)7 * H1_ * D_ * 2;        //  29.4 MB (6 experts + gate)
    bf16_t* w2t   = (bf16_t*)ws;  ws += (size_t)E_ * H2_ * H1_ * 2;      //   6.3 MB
    bf16_t* h1    = (bf16_t*)ws;  ws += (size_t)7 * B_ * H1_ * 2;        // 117.4 MB (slice 6 = gate g)
    bf16_t* h2    = (bf16_t*)ws;  ws += (size_t)E_ * B_ * H2_ * 2;       //  50.3 MB
    float*  bias7 = (float*)ws;   ws += (size_t)7 * H1_ * 4;             //  28 KB
    float*  gate  = (float*)ws;   ws += (size_t)T_ * B_ * EC_ * 4;       //   0.3 MB

    bf16_t* wgt = w1t + (size_t)6 * H1_ * D_;   // gate weights = expert slice 6

    // 0) bias concat (d2d async, graph-capture safe)
    hipMemcpyAsync(bias7, be1, (size_t)E_ * H1_ * sizeof(float),
                   hipMemcpyDeviceToDevice, stream);
    hipMemcpyAsync(bias7 + (size_t)E_ * H1_, bg1, (size_t)T_ * G_ * sizeof(float),
                   hipMemcpyDeviceToDevice, stream);

    // 1) casts / transposes
    cast_x_kernel<<<(B_ * D_ / 8) / 256, 256, 0, stream>>>(x, x_bf, B_ * D_ / 8);
    dim3 tb(32, 8);
    transpose_cast_kernel<<<dim3(H1_ / 32, D_ / 32, E_),  tb, 0, stream>>>(We1, w1t, D_,  H1_);
    transpose_cast_kernel<<<dim3(H2_ / 32, H1_ / 32, E_), tb, 0, stream>>>(We2, w2t, H1_, H2_);
    transpose_cast_kernel<<<dim3(G_ / 32, D_ / 32, T_),   tb, 0, stream>>>(Wg1, wgt, D_,  G_);

    // 2) GEMM1 + gate folded (z = 0..5 experts, z = 6 gate), 8-phase 1-barrier
    gemm256_8p1b<<<dim3(H1_ / 256, B_ / 256, 7), 512, 0, stream>>>(
        x_bf, w1t, bias7, h1, B_, H1_, D_, 0LL);
    // 3) GEMM2 over experts 0..5 on the r4-proven 128x256 kernel
    gemm_bn256_bias_relu<<<dim3(H2_ / 256, B_ / 128, E_), 512, 0, stream>>>(
        h1, w2t, be2, h2, B_, H2_, H1_, (long long)B_ * H1_);

    // 4) gate softmax + final combine
    gate_kernel<<<(T_ * B_) / 4, 256, 0, stream>>>(h1, Wgs, gate);
    combine_kernel<<<((size_t)T_ * B_ * H2_ / 8) / 256, 256, 0, stream>>>(h2, gate, out);
}

// Round 9
// 363.652 us; speedup vs baseline: 1.8751x; 1.0554x over previous
//
#include <hip/hip_runtime.h>
#include <hip/hip_bf16.h>
#include <cstdint>
#include <cstddef>

#define B_   8192
#define D_   2048
#define H1_  1024
#define H2_  512
#define G_   512
#define T_   2
#define E_   6
#define EC_  4

typedef __bf16 bf16_t;
typedef __attribute__((ext_vector_type(8))) __bf16 bf16x8;
typedef __attribute__((ext_vector_type(4))) float f32x4;
typedef __attribute__((ext_vector_type(16))) float f32x16;

// ---------------------------------------------------------------------------
// async global->LDS, 16B per lane. LDS dest is wave-uniform base + lane*16.
// ---------------------------------------------------------------------------
__device__ __forceinline__ void gload_lds16(const bf16_t* g, bf16_t* l) {
    __builtin_amdgcn_global_load_lds(
        (const __attribute__((address_space(1))) bf16_t*)g,
        (__attribute__((address_space(3))) bf16_t*)l,
        16, 0, 0);
}

// ---------------------------------------------------------------------------
// cast x (fp32) -> bf16, 8 elems/thread
// ---------------------------------------------------------------------------
__global__ __launch_bounds__(256) void cast_x_kernel(
    const float* __restrict__ src, bf16_t* __restrict__ dst, int n8)
{
    int i = blockIdx.x * blockDim.x + threadIdx.x;
    if (i >= n8) return;
    const float4* s = (const float4*)src + (size_t)i * 2;
    float4 a = s[0], b = s[1];
    bf16x8 o;
    o[0] = (bf16_t)a.x; o[1] = (bf16_t)a.y; o[2] = (bf16_t)a.z; o[3] = (bf16_t)a.w;
    o[4] = (bf16_t)b.x; o[5] = (bf16_t)b.y; o[6] = (bf16_t)b.z; o[7] = (bf16_t)b.w;
    *(bf16x8*)(dst + (size_t)i * 8) = o;
}

// ---------------------------------------------------------------------------
// transpose + cast: src (batch, R, C) fp32 -> dst (batch, C, R) bf16
// ---------------------------------------------------------------------------
__global__ __launch_bounds__(256) void transpose_cast_kernel(
    const float* __restrict__ src, bf16_t* __restrict__ dst, int R, int C)
{
    __shared__ float tile[32][33];
    int bz = blockIdx.z;
    src += (size_t)bz * R * C;
    dst += (size_t)bz * R * C;
    int c0 = blockIdx.x * 32, r0 = blockIdx.y * 32;
    int tx = threadIdx.x, ty = threadIdx.y;
#pragma unroll
    for (int i = 0; i < 32; i += 8)
        tile[ty + i][tx] = src[(size_t)(r0 + ty + i) * C + (c0 + tx)];
    __syncthreads();
#pragma unroll
    for (int i = 0; i < 32; i += 8)
        dst[(size_t)(c0 + ty + i) * R + (r0 + tx)] = (bf16_t)tile[tx][ty + i];
}

// ---------------------------------------------------------------------------
// 256x256-tile, BK=64, 8-phase single-barrier GEMM with 32x32x16 MFMA (r9):
//   C = relu(A(M,K) * Bt(N,K)^T + bias), bf16 in/out, fp32 MFMA accumulate.
// Same r8-proven staging/barrier/vmcnt structure; CHANGE: MFMA shape
// 32x32x16 (2495 TF ceiling vs 2075 for 16x16x32; half the instructions).
// 8 waves (2Mx4N), per-wave 128x64 = 4 m-blocks x 2 n-blocks of 32x32,
// acc = f32x16[4][2] (128 AGPR). Phase qm = m-block; 8 MFMA/phase.
// A-frag (32x32x16): row = lane&31, k = kstep*16 + (lane>>5)*8 (b128 read).
// C/D: col = lane&31, row = (reg&3)+8*(reg>>2)+4*(lane>>5)  [m74/m101].
// Chunk-XOR swizzle phys = logical ^ (row&7) on both stage-source and reads;
// per-octet phys chunks distinct -> conflict-free (same argument as r8).
// bias: e<6 -> be1+e*H1, e==6 -> bg1 (1024 contiguous floats = slice-6 cols).
// Requires: M%256==0, N%256==0, K%128==0, K/64>=4, gridX*gridY%8==0.
// ---------------------------------------------------------------------------
__global__ __launch_bounds__(512, 2) void gemm256_8p_w32(
    const bf16_t* __restrict__ A, const bf16_t* __restrict__ Bt,
    const float* __restrict__ be1, const float* __restrict__ bg1,
    bf16_t* __restrict__ C, int M, int N, int K, long long strideA)
{
    const int e = blockIdx.z;
    A  += (size_t)e * (size_t)strideA;
    Bt += (size_t)e * (size_t)N * (size_t)K;
    C  += (size_t)e * (size_t)M * (size_t)N;
    const float* bias = (e < 6) ? (be1 + (size_t)e * H1_) : bg1;

    // T1: XCD swizzle within this z-slice (nwg % 8 == 0 by launch contract)
    const int gx  = gridDim.x;
    const int nwg = gx * gridDim.y;
    const int lin = blockIdx.y * gx + blockIdx.x;
    const int swz = (lin & 7) * (nwg >> 3) + (lin >> 3);
    const int row0 = (swz / gx) * 256;
    const int col0 = (swz % gx) * 256;

    __shared__ bf16_t lsA[2][16384];   // [dbuf][256 rows x 64], 64 KB
    __shared__ bf16_t lsB[2][16384];   // 64 KB

    const int tid  = threadIdx.x;
    const int lane = tid & 63;
    const int wave = tid >> 6;        // 0..7
    const int wr   = wave >> 2;       // 0..1 : M-half (128 rows)
    const int wc   = wave & 3;        // 0..3 : N-quarter (64 cols)

    // ---- staging (unchanged from r8): half-tile = 128 rows x 8 chunks(16B) -
    size_t offG[2];
    int    ldsOff[2];
#pragma unroll
    for (int l = 0; l < 2; ++l) {
        int idx = l * 512 + tid;
        int r   = idx >> 3;                       // row within half, 0..127
        int c   = (idx & 7) ^ (r & 7);            // logical chunk
        offG[l]   = (size_t)r * (size_t)K + (size_t)(c * 8);
        ldsOff[l] = l * 4096 + wave * 512;        // elements, wave-uniform
    }
    const bf16_t* gA = A  + (size_t)row0 * (size_t)K;
    const bf16_t* gB = Bt + (size_t)col0 * (size_t)K;
    const size_t halfStride = (size_t)128 * (size_t)K;

    // ---- fragment read addressing for 32x32x16 ------------------------------
    // row = base + (lane&31); logical chunk = kstep*2 + (lane>>5);
    // phys = logical ^ (row&7) = logical ^ (lane&7)  (row bases % 8 == 0)
    const int rbA = (wr * 128 + (lane & 31)) * 64;
    const int rbB = (wc * 64  + (lane & 31)) * 64;
    const int lh  = lane >> 5;
    int kx[4];
#pragma unroll
    for (int k = 0; k < 4; ++k)
        kx[k] = ((k * 2 + lh) ^ (lane & 7)) * 8;

    f32x16 acc[4][2];
#pragma unroll
    for (int m = 0; m < 4; ++m)
#pragma unroll
        for (int n = 0; n < 2; ++n)
#pragma unroll
            for (int r = 0; r < 16; ++r)
                acc[m][n][r] = 0.f;

    const int nt    = K >> 6;         // K-tiles of 64
    const int niter = nt >> 1;        // 2 K-tiles per iteration

#define STAGE_A(dst, kt, h) do {                                              \
    _Pragma("unroll")                                                         \
    for (int l_ = 0; l_ < 2; ++l_)                                            \
        gload_lds16(gA + (size_t)((kt) * 64) + (size_t)(h) * halfStride       \
                       + offG[l_],                                            \
                    &lsA[dst][(h) * 8192 + ldsOff[l_]]);                      \
} while (0)

#define STAGE_B(dst, kt, h) do {                                              \
    _Pragma("unroll")                                                         \
    for (int l_ = 0; l_ < 2; ++l_)                                            \
        gload_lds16(gB + (size_t)((kt) * 64) + (size_t)(h) * halfStride       \
                       + offG[l_],                                            \
                    &lsB[dst][(h) * 8192 + ldsOff[l_]]);                      \
} while (0)

// phase qm (m-block) of dbuf d: {4 A-reads [+8 B-reads if qm==0]; stage;
// optional vmcnt; barrier; lgkm(0); 8 MFMA 32x32x16}.
#define PHASE(d, qm, STMT, WAITV) do {                                        \
    bf16x8 af0, af1, af2, af3;                                                \
    af0 = *(const bf16x8*)&lsA[d][rbA + (qm) * 2048 + kx[0]];                 \
    af1 = *(const bf16x8*)&lsA[d][rbA + (qm) * 2048 + kx[1]];                 \
    af2 = *(const bf16x8*)&lsA[d][rbA + (qm) * 2048 + kx[2]];                 \
    af3 = *(const bf16x8*)&lsA[d][rbA + (qm) * 2048 + kx[3]];                 \
    if ((qm) == 0) {                                                          \
        _Pragma("unroll")                                                     \
        for (int n_ = 0; n_ < 2; ++n_)                                        \
            _Pragma("unroll")                                                 \
            for (int k_ = 0; k_ < 4; ++k_)                                    \
                bfr[n_][k_] = *(const bf16x8*)&lsB[d][rbB + n_ * 2048 + kx[k_]]; \
    }                                                                         \
    STMT;                                                                     \
    WAITV;                                                                    \
    __builtin_amdgcn_sched_barrier(0);                                        \
    __builtin_amdgcn_s_barrier();                                             \
    asm volatile("s_waitcnt lgkmcnt(0)" ::: "memory");                        \
    __builtin_amdgcn_sched_barrier(0);                                        \
    __builtin_amdgcn_s_setprio(1);                                            \
    acc[qm][0] = __builtin_amdgcn_mfma_f32_32x32x16_bf16(af0, bfr[0][0], acc[qm][0], 0, 0, 0); \
    acc[qm][1] = __builtin_amdgcn_mfma_f32_32x32x16_bf16(af0, bfr[1][0], acc[qm][1], 0, 0, 0); \
    acc[qm][0] = __builtin_amdgcn_mfma_f32_32x32x16_bf16(af1, bfr[0][1], acc[qm][0], 0, 0, 0); \
    acc[qm][1] = __builtin_amdgcn_mfma_f32_32x32x16_bf16(af1, bfr[1][1], acc[qm][1], 0, 0, 0); \
    acc[qm][0] = __builtin_amdgcn_mfma_f32_32x32x16_bf16(af2, bfr[0][2], acc[qm][0], 0, 0, 0); \
    acc[qm][1] = __builtin_amdgcn_mfma_f32_32x32x16_bf16(af2, bfr[1][2], acc[qm][1], 0, 0, 0); \
    acc[qm][0] = __builtin_amdgcn_mfma_f32_32x32x16_bf16(af3, bfr[0][3], acc[qm][0], 0, 0, 0); \
    acc[qm][1] = __builtin_amdgcn_mfma_f32_32x32x16_bf16(af3, bfr[1][3], acc[qm][1], 0, 0, 0); \
    __builtin_amdgcn_s_setprio(0);                                            \
    __builtin_amdgcn_sched_barrier(0);                                        \
} while (0)

    // ---- prologue: A(0),B(0) -> buf0; B(1) -> buf1; drain to 4 -------------
    STAGE_A(0, 0, 0); STAGE_A(0, 0, 1);
    STAGE_B(0, 0, 0); STAGE_B(0, 0, 1);
    STAGE_B(1, 1, 0); STAGE_B(1, 1, 1);
    asm volatile("s_waitcnt vmcnt(4)" ::: "memory");   // A(0),B(0) complete
    __builtin_amdgcn_sched_barrier(0);
    __builtin_amdgcn_s_barrier();
    __builtin_amdgcn_sched_barrier(0);

    // ---- main loop: iter i computes kt0=2i (buf0, p0-3), kt1=2i+1 (buf1) ---
    for (int i = 0; i < niter; ++i) {
        const int kt0 = 2 * i, kt1 = 2 * i + 1;
        const bool stg = (i + 1 < niter);
        bf16x8 bfr[2][4];

        PHASE(0, 0, { STAGE_A(1, kt1, 0); }, {});
        PHASE(0, 1, { STAGE_A(1, kt1, 1); }, {});
        PHASE(0, 2, { if (stg) STAGE_B(0, kt0 + 2, 0); }, {});
        PHASE(0, 3, { if (stg) STAGE_B(0, kt0 + 2, 1); },
              { if (stg) { asm volatile("s_waitcnt vmcnt(4)" ::: "memory"); }
                else     { asm volatile("s_waitcnt vmcnt(0)" ::: "memory"); } });
        PHASE(1, 0, { if (stg) STAGE_A(0, kt0 + 2, 0); }, {});
        PHASE(1, 1, { if (stg) STAGE_A(0, kt0 + 2, 1); }, {});
        PHASE(1, 2, { if (stg) STAGE_B(1, kt0 + 3, 0); }, {});
        PHASE(1, 3, { if (stg) STAGE_B(1, kt0 + 3, 1); },
              { if (stg) { asm volatile("s_waitcnt vmcnt(4)" ::: "memory"); } });
    }
#undef PHASE
#undef STAGE_A
#undef STAGE_B

    // ---- epilogue: 32x32 C/D layout (m74/m101-verified):
    // col = lane&31, row = (reg&3) + 8*(reg>>2) + 4*(lane>>5)
    const int crb = row0 + wr * 128 + 4 * lh;
    const int ccb = col0 + wc * 64  + (lane & 31);
#pragma unroll
    for (int qm = 0; qm < 4; ++qm) {
#pragma unroll
        for (int n = 0; n < 2; ++n) {
            const int cc = ccb + n * 32;
            const float bv = bias[cc];
#pragma unroll
            for (int r = 0; r < 16; ++r) {
                const int row = crb + qm * 32 + (r & 3) + 8 * (r >> 2);
                float v = acc[qm][n][r] + bv;
                v = v > 0.f ? v : 0.f;
                C[(size_t)row * N + cc] = (bf16_t)v;
            }
        }
    }
}

// ---------------------------------------------------------------------------
// r4-proven 128x256 GEMM, 2 blocks/CU — used for GEMM2.
// ---------------------------------------------------------------------------
__global__ __launch_bounds__(512, 4) void gemm_bn256_bias_relu(
    const bf16_t* __restrict__ A, const bf16_t* __restrict__ Bt,
    const float* __restrict__ bias, bf16_t* __restrict__ C,
    int M, int N, int K, long long strideA)
{
    const int e = blockIdx.z;
    A    += (size_t)e * (size_t)strideA;
    Bt   += (size_t)e * (size_t)N * (size_t)K;
    bias += (size_t)e * (size_t)N;
    C    += (size_t)e * (size_t)M * (size_t)N;

    const int gx  = gridDim.x;
    const int nwg = gx * gridDim.y;
    const int lin = blockIdx.y * gx + blockIdx.x;
    const int swz = (lin & 7) * (nwg >> 3) + (lin >> 3);
    const int row0 = (swz / gx) * 128;
    const int col0 = (swz % gx) * 256;

    __shared__ bf16_t lsA[3][128 * 32];   // 3 x 8 KB
    __shared__ bf16_t lsB[3][256 * 32];   // 3 x 16 KB   -> 72 KB total

    const int tid  = threadIdx.x;
    const int lane = tid & 63;
    const int wave = tid >> 6;        // 0..7
    const int wr   = wave >> 2;       // 0..1 : 64-row half
    const int wc   = wave & 3;        // 0..3 : 64-col quarter

    size_t offA, offB0, offB1;
    {
        int rA = tid >> 2, pA = tid & 3;
        offA = (size_t)rA * (size_t)K + (size_t)(((pA ^ (rA >> 1)) & 3) * 8);
        int r0_ = tid >> 2, p0_ = tid & 3;
        offB0 = (size_t)r0_ * (size_t)K + (size_t)(((p0_ ^ (r0_ >> 1)) & 3) * 8);
        int r1_ = (512 + tid) >> 2, p1_ = tid & 3;
        offB1 = (size_t)r1_ * (size_t)K + (size_t)(((p1_ ^ (r1_ >> 1)) & 3) * 8);
    }
    const int ldsA_off = wave * 512;
    const int ldsB0off = wave * 512;
    const int ldsB1off = 4096 + wave * 512;

    const bf16_t* gA = A  + (size_t)row0 * (size_t)K;
    const bf16_t* gB = Bt + (size_t)col0 * (size_t)K;

    const int xch  = ((lane >> 4) ^ ((lane >> 1) & 3)) << 3;
    const int aoff = (wr * 64 + (lane & 15)) * 32 + xch;
    const int boff = (wc * 64 + (lane & 15)) * 32 + xch;

    f32x4 acc[4][4];
#pragma unroll
    for (int m = 0; m < 4; ++m)
#pragma unroll
        for (int n = 0; n < 4; ++n)
            acc[m][n] = (f32x4){0.f, 0.f, 0.f, 0.f};

    const int nt = K >> 5;

#define STAGE(t_, c_) do {                                                    \
    const size_t kk_ = (size_t)(t_) * 32;                                     \
    gload_lds16(gA + kk_ + offA,  &lsA[c_][ldsA_off]);                        \
    gload_lds16(gB + kk_ + offB0, &lsB[c_][ldsB0off]);                        \
    gload_lds16(gB + kk_ + offB1, &lsB[c_][ldsB1off]);                        \
} while (0)

    STAGE(0, 0); STAGE(1, 1); STAGE(2, 2);
    asm volatile("s_waitcnt vmcnt(6)" ::: "memory");
    __builtin_amdgcn_s_barrier();
    __builtin_amdgcn_sched_barrier(0);

    int c = 0;
    for (int t = 0; t < nt; ++t) {
        bf16x8 a[4], b[4];
#pragma unroll
        for (int m = 0; m < 4; ++m)
            a[m] = *(const bf16x8*)&lsA[c][aoff + m * 512];
#pragma unroll
        for (int n = 0; n < 4; ++n)
            b[n] = *(const bf16x8*)&lsB[c][boff + n * 512];
        asm volatile("s_waitcnt lgkmcnt(0)" ::: "memory");
        __builtin_amdgcn_sched_barrier(0);
        __builtin_amdgcn_s_barrier();
        __builtin_amdgcn_sched_barrier(0);
        if (t + 3 < nt) STAGE(t + 3, c);
        __builtin_amdgcn_sched_barrier(0);
        __builtin_amdgcn_s_setprio(1);
#pragma unroll
        for (int m = 0; m < 4; ++m)
#pragma unroll
            for (int n = 0; n < 4; ++n)
                acc[m][n] = __builtin_amdgcn_mfma_f32_16x16x32_bf16(
                                a[m], b[n], acc[m][n], 0, 0, 0);
        __builtin_amdgcn_s_setprio(0);
        __builtin_amdgcn_sched_barrier(0);
        if (t + 3 < nt) { asm volatile("s_waitcnt vmcnt(6)" ::: "memory"); }
        else            { asm volatile("s_waitcnt vmcnt(0)" ::: "memory"); }
        __builtin_amdgcn_sched_barrier(0);
        __builtin_amdgcn_s_barrier();
        __builtin_amdgcn_sched_barrier(0);
        c = (c == 2) ? 0 : c + 1;
    }
#undef STAGE

    const int crb = row0 + wr * 64 + ((lane >> 4) << 2);
    const int ccb = col0 + wc * 64 + (lane & 15);
#pragma unroll
    for (int n = 0; n < 4; ++n) {
        const int cc = ccb + n * 16;
        const float bv = bias[cc];
#pragma unroll
        for (int m = 0; m < 4; ++m) {
            const int rb = crb + m * 16;
#pragma unroll
            for (int j = 0; j < 4; ++j) {
                float v = acc[m][n][j] + bv;
                v = v > 0.f ? v : 0.f;
                C[(size_t)(rb + j) * N + cc] = (bf16_t)v;
            }
        }
    }
}

// ---------------------------------------------------------------------------
// fused gate + combine: per wave, one (t,b) row.
// Step 1: logits[e'] = sum_g h1gate[t,b,g] * Wgs[t,g,e']; butterfly reduce
//         (all lanes get totals), per-lane softmax -> g0..g3.
// Step 2: out[t,b,o0..o0+7] = sum_j g_j * h2[IDX[t][j], b, o0..]; o0=lane*8.
// IDX[t] = {2t, 2t+1, 4, 5}. Grid: (T*B/4) blocks x 256 threads (4 waves).
// ---------------------------------------------------------------------------
__global__ __launch_bounds__(256) void gate_combine_kernel(
    const bf16_t* __restrict__ h1, const bf16_t* __restrict__ h2,
    const float* __restrict__ Wgs, float* __restrict__ out)
{
    int wid  = blockIdx.x * 4 + (threadIdx.x >> 6);   // t*B + b
    int lane = threadIdx.x & 63;
    int t = wid >> 13;                                // B_ = 8192
    int b = wid & (B_ - 1);

    // ---- gate logits ----
    const bf16_t* grow = h1 + ((size_t)(6 * B_) + b) * 1024 + t * G_;
    bf16x8 gv = *(const bf16x8*)&grow[lane * 8];
    const float* W = Wgs + (size_t)t * G_ * EC_;
    float a0 = 0.f, a1 = 0.f, a2 = 0.f, a3 = 0.f;
#pragma unroll
    for (int i = 0; i < 8; ++i) {
        float gvf = (float)gv[i];
        const float4 w = *(const float4*)&W[(size_t)(lane * 8 + i) * 4];
        a0 += gvf * w.x; a1 += gvf * w.y; a2 += gvf * w.z; a3 += gvf * w.w;
    }
#pragma unroll
    for (int off = 32; off; off >>= 1) {
        a0 += __shfl_xor(a0, off);
        a1 += __shfl_xor(a1, off);
        a2 += __shfl_xor(a2, off);
        a3 += __shfl_xor(a3, off);
    }
    // ---- softmax (every lane computes the same values) ----
    float m  = fmaxf(fmaxf(a0, a1), fmaxf(a2, a3));
    float e0 = expf(a0 - m), e1 = expf(a1 - m), e2 = expf(a2 - m), e3 = expf(a3 - m);
    float inv = 1.f / (e0 + e1 + e2 + e3);
    float g0 = e0 * inv, g1 = e1 * inv, g2 = e2 * inv, g3 = e3 * inv;

    // ---- combine: 8 outputs per lane ----
    int o0 = lane * 8;                                // H2 = 512 = 64*8
    const bf16x8 v0 = *(const bf16x8*)&h2[((size_t)(2 * t)     * B_ + b) * H2_ + o0];
    const bf16x8 v1 = *(const bf16x8*)&h2[((size_t)(2 * t + 1) * B_ + b) * H2_ + o0];
    const bf16x8 v2 = *(const bf16x8*)&h2[((size_t)4           * B_ + b) * H2_ + o0];
    const bf16x8 v3 = *(const bf16x8*)&h2[((size_t)5           * B_ + b) * H2_ + o0];
    float r[8];
#pragma unroll
    for (int i = 0; i < 8; ++i)
        r[i] = g0 * (float)v0[i] + g1 * (float)v1[i]
             + g2 * (float)v2[i] + g3 * (float)v3[i];
    float4* op = (float4*)&out[(size_t)wid * H2_ + o0];
    op[0] = make_float4(r[0], r[1], r[2], r[3]);
    op[1] = make_float4(r[4], r[5], r[6], r[7]);
}

// ---------------------------------------------------------------------------
extern "C" void kernel_launch(void* const* d_in, const int* in_sizes, int n_in,
                              void* d_out, int out_size, void* d_ws, size_t ws_size,
                              hipStream_t stream)
{
    const float* x   = (const float*)d_in[0];
    const float* We1 = (const float*)d_in[1];
    const float* be1 = (const float*)d_in[2];
    const float* We2 = (const float*)d_in[3];
    const float* be2 = (const float*)d_in[4];
    const float* Wg1 = (const float*)d_in[5];
    const float* bg1 = (const float*)d_in[6];
    const float* Wgs = (const float*)d_in[7];
    float* out = (float*)d_out;

    char* ws = (char*)d_ws;
    bf16_t* x_bf = (bf16_t*)ws;  ws += (size_t)B_ * D_ * 2;              //  33.6 MB
    bf16_t* w1t  = (bf16_t*)ws;  ws += (size_t)7 * H1_ * D_ * 2;         //  29.4 MB (6 experts + gate)
    bf16_t* w2t  = (bf16_t*)ws;  ws += (size_t)E_ * H2_ * H1_ * 2;       //   6.3 MB
    bf16_t* h1   = (bf16_t*)ws;  ws += (size_t)7 * B_ * H1_ * 2;         // 117.4 MB (slice 6 = gate g)
    bf16_t* h2   = (bf16_t*)ws;  ws += (size_t)E_ * B_ * H2_ * 2;        //  50.3 MB

    bf16_t* wgt = w1t + (size_t)6 * H1_ * D_;   // gate weights = expert slice 6

    // 1) casts / transposes
    cast_x_kernel<<<(B_ * D_ / 8) / 256, 256, 0, stream>>>(x, x_bf, B_ * D_ / 8);
    dim3 tb(32, 8);
    transpose_cast_kernel<<<dim3(H1_ / 32, D_ / 32, E_),  tb, 0, stream>>>(We1, w1t, D_,  H1_);
    transpose_cast_kernel<<<dim3(H2_ / 32, H1_ / 32, E_), tb, 0, stream>>>(We2, w2t, H1_, H2_);
    transpose_cast_kernel<<<dim3(G_ / 32, D_ / 32, T_),   tb, 0, stream>>>(Wg1, wgt, D_,  G_);

    // 2) GEMM1 + gate folded (z = 0..5 experts, z = 6 gate), 32x32 8-phase
    gemm256_8p_w32<<<dim3(H1_ / 256, B_ / 256, 7), 512, 0, stream>>>(
        x_bf, w1t, be1, bg1, h1, B_, H1_, D_, 0LL);
    // 3) GEMM2 over experts 0..5 on the r4-proven 128x256 kernel
    gemm_bn256_bias_relu<<<dim3(H2_ / 256, B_ / 128, E_), 512, 0, stream>>>(
        h1, w2t, be2, h2, B_, H2_, H1_, (long long)B_ * H1_);

    // 4) fused gate softmax + combine
    gate_combine_kernel<<<(T_ * B_) / 4, 256, 0, stream>>>(h1, h2, Wgs, out);
}